// Round 17
// baseline (152.447 us; speedup 1.0000x reference)
//
#include <hip/hip_runtime.h>
#include <hip/hip_bf16.h>

#define DIM 128
#define BNODES 64       // fine bucket = 64 dst nodes (dst>>6)
#define CNODES 1024     // coarse bucket = 1024 dst nodes (dst>>10)
#define NCMAX 128       // coarse cursor capacity (ncb = 98 for N=100000)
#define NBMAX 2048      // fine cursor capacity (nb = 1563)
#define CCAP 20480      // edges per coarse region (mean 16327, +32 sigma)
#define BCAP 2048       // edges per fine region (mean 1024, +32 sigma)
#define FB 16           // fine targets per coarse region (CNODES/BNODES)
#define CCHUNK 2048     // edges per coarse block (LDS staging capacity)

typedef __attribute__((ext_vector_type(8))) short bf16x8;
typedef __attribute__((ext_vector_type(4))) float f32x4;

__device__ inline ushort f2bf(float f) {
    uint u = __float_as_uint(f);
    u += 0x7fffu + ((u >> 16) & 1u);   // RNE
    return (ushort)(u >> 16);
}
__device__ inline uint pack2(float lo, float hi) {
    return (uint)f2bf(lo) | ((uint)f2bf(hi) << 16);
}

// ---- MFMA lin1 body (round-3-proven), tile-range parameterized --------------
// msg[n][j] = bf16(relu(bm[j] + sum_k x[n][k]*Wm[j][k])) for tiles
// [tile0, tile0+tcount). A/B share an assumed k-bijection (dot invariant);
// C layout m89-verified: col=lane&15, row=(lane>>4)*4+reg.
__device__ __forceinline__
void lin1_body(const float* __restrict__ in, const float* __restrict__ W,
               const float* __restrict__ b, ushort* __restrict__ out,
               int tile0, int tcount, int bid, int nblocks, uint4* Wl)
{
    const int t = threadIdx.x;
    for (int q = t; q < 2048; q += 256) {
        const int j = q >> 4, c = q & 15;
        const float4 lo = ((const float4*)(W + j * 128 + c * 8))[0];
        const float4 hi = ((const float4*)(W + j * 128 + c * 8))[1];
        uint4 pk;
        pk.x = pack2(lo.x, lo.y); pk.y = pack2(lo.z, lo.w);
        pk.z = pack2(hi.x, hi.y); pk.w = pack2(hi.z, hi.w);
        Wl[j * 16 + (c ^ (j & 15))] = pk;
    }
    __syncthreads();

    const int lane = t & 63;
    const int lo4 = lane & 15;
    const int g   = lane >> 4;

    float bias[8];
    #pragma unroll
    for (int ct = 0; ct < 8; ++ct) bias[ct] = b[ct * 16 + lo4];

    const int wid = (bid * 256 + t) >> 6;
    const int nw  = (nblocks * 256) >> 6;
    const int tend = tile0 + tcount;

    for (int tile = tile0 + wid; tile < tend; tile += nw) {
        const int arow = tile * 16 + lo4;
        const float4* ap = (const float4*)(in + (size_t)arow * DIM + g * 32);
        float4 v[8];
        #pragma unroll
        for (int i = 0; i < 8; ++i) v[i] = ap[i];

        bf16x8 afrag[4];
        #pragma unroll
        for (int ks = 0; ks < 4; ++ks) {
            union { bf16x8 v8; uint u[4]; } a;
            a.u[0] = pack2(v[2*ks].x,   v[2*ks].y);
            a.u[1] = pack2(v[2*ks].z,   v[2*ks].w);
            a.u[2] = pack2(v[2*ks+1].x, v[2*ks+1].y);
            a.u[3] = pack2(v[2*ks+1].z, v[2*ks+1].w);
            afrag[ks] = a.v8;
        }

        f32x4 acc[8];
        #pragma unroll
        for (int ct = 0; ct < 8; ++ct)
            acc[ct] = (f32x4){bias[ct], bias[ct], bias[ct], bias[ct]};

        #pragma unroll
        for (int ks = 0; ks < 4; ++ks) {
            #pragma unroll
            for (int ct = 0; ct < 8; ++ct) {
                const int jrow = ct * 16 + lo4;
                const bf16x8 bfrag = *((const bf16x8*)&Wl[jrow * 16 + ((g * 4 + ks) ^ lo4)]);
                acc[ct] = __builtin_amdgcn_mfma_f32_16x16x32_bf16(afrag[ks], bfrag, acc[ct], 0, 0, 0);
            }
        }

        #pragma unroll
        for (int ct = 0; ct < 8; ++ct) {
            #pragma unroll
            for (int r = 0; r < 4; ++r) {
                const int orow = tile * 16 + g * 4 + r;
                const int ocol = ct * 16 + lo4;
                out[(size_t)orow * DIM + ocol] = f2bf(fmaxf(acc[ct][r], 0.f));
            }
        }
    }
}

// ---- fused A: coarse counting-sort (parity-even) || lin1 tiles [0, half) ----
// [round-15 proven: fusion beats serial by ~6.5us — real pipe overlap]
__global__ __launch_bounds__(256, 2)
void fusedA_kernel(const float* x, const float* __restrict__ Wm,
                   const float* __restrict__ bm, ushort* msg,
                   int tile0, int tcount, int lb,
                   const int* __restrict__ ei, int* __restrict__ ccur,
                   uint* __restrict__ cedges, int n_edges, int ncb, int cb)
{
    __shared__ uint4 Wl[128 * 16];   // 32 KB; coarse path overlays sort buffers

    const int bid = (int)blockIdx.x;
    bool coarse;
    int rid;
    if (bid < 2 * cb) { coarse = !(bid & 1); rid = bid >> 1; }
    else              { coarse = false;      rid = cb + (bid - 2 * cb); }

    if (coarse) {
        uint*   packedL = (uint*)Wl;                    // 8 KB
        ushort* regionL = (ushort*)(packedL + CCHUNK);  // 4 KB
        int*    histC   = (int*)(regionL + CCHUNK);     // 512 B
        int*    startC  = histC + NCMAX;
        int*    gbaseC  = startC + NCMAX;
        int*    curC    = gbaseC + NCMAX;

        const int t = threadIdx.x;
        const int chunk = (n_edges + cb - 1) / cb;      // 2047 <= CCHUNK
        const int e0 = rid * chunk;
        const int e1 = min(e0 + chunk, n_edges);
        const int cnt = e1 - e0;

        if (t < NCMAX) histC[t] = 0;
        __syncthreads();
        for (int i = t; i < cnt; i += 256)
            atomicAdd(&histC[ei[n_edges + e0 + i] >> 10], 1);
        __syncthreads();
        if (t < NCMAX) startC[t] = histC[t];
        for (int off = 1; off < NCMAX; off <<= 1) {
            int add = 0;
            __syncthreads();
            if (t < NCMAX && t >= off) add = startC[t - off];
            __syncthreads();
            if (t < NCMAX) startC[t] += add;
        }
        __syncthreads();
        if (t < NCMAX) {
            const int excl = startC[t] - histC[t];
            startC[t] = excl;
            curC[t] = excl;
            gbaseC[t] = (t < ncb && histC[t]) ? atomicAdd(&ccur[t], histC[t]) : 0;
        }
        __syncthreads();
        for (int i = t; i < cnt; i += 256) {
            const int src = ei[e0 + i];
            const int dst = ei[n_edges + e0 + i];
            const int r = dst >> 10;
            const int pos = atomicAdd(&curC[r], 1);
            packedL[pos] = ((uint)src << 10) | (uint)(dst & 1023);
            regionL[pos] = (ushort)r;
        }
        __syncthreads();
        for (int i = t; i < cnt; i += 256) {
            const int r = regionL[i];
            const int off = gbaseC[r] + (i - startC[r]);
            if (off < CCAP)
                cedges[(size_t)r * CCAP + off] = packedL[i];   // coalesced runs
        }
    } else {
        lin1_body(x, Wm, bm, msg, tile0, tcount, rid, lb, Wl);
    }
}

// ---- fused B: fine scatter (parity-even) || lin1 tiles [half, n_tiles) ------
// Fine refines each coarse region into its 16 fine buckets (dst>>6);
// contiguous reads, ~1KB write runs. [round-12 proven body]
__global__ __launch_bounds__(256, 2)
void fusedB_kernel(const float* x, const float* __restrict__ Wm,
                   const float* __restrict__ bm, ushort* msg,
                   int tile0, int tcount, int lb,
                   const int* __restrict__ ccnt, const uint* __restrict__ cedges,
                   int* __restrict__ gcur, uint* __restrict__ bedges,
                   int ncb, int fb)
{
    __shared__ uint4 Wl[128 * 16];   // lin path
    __shared__ int histL[FB];
    __shared__ int curL[FB];

    const int bid = (int)blockIdx.x;
    bool fine;
    int rid;
    if (bid < 2 * fb) { fine = !(bid & 1); rid = bid >> 1; }
    else              { fine = false;      rid = fb + (bid - 2 * fb); }

    if (fine) {
        const int t = threadIdx.x;
        const int c = rid >> 3;
        const int s = rid & 7;
        const int cnt = min(ccnt[c], CCAP);
        const int chunk = (cnt + 7) / 8;
        const int e0 = s * chunk;
        const int e1 = min(e0 + chunk, cnt);
        if (t < FB) histL[t] = 0;
        __syncthreads();
        const uint* ce = cedges + (size_t)c * CCAP;
        for (int i = e0 + t; i < e1; i += 256)
            atomicAdd(&histL[(ce[i] & 1023u) >> 6], 1);
        __syncthreads();
        if (t < FB)
            curL[t] = histL[t] ? atomicAdd(&gcur[c * FB + t], histL[t]) : 0;
        __syncthreads();
        for (int i = e0 + t; i < e1; i += 256) {
            const uint p = ce[i];
            const uint dl = p & 1023u;
            const int f = (int)(dl >> 6);
            const int pos = atomicAdd(&curL[f], 1);
            if (pos < BCAP)
                bedges[(size_t)(c * FB + f) * BCAP + pos] = ((p >> 10) << 6) | (dl & 63u);
        }
    } else {
        lin1_body(x, Wm, bm, msg, tile0, tcount, rid, lb, Wl);
    }
}

// Per-bucket gather [round-12/14 proven]: hist + scan + sort (int LDS atomics),
// pull with 8-deep MLP, deposit packed-bf16 agg row (a16 handoff).
__global__ __launch_bounds__(512)
void bucket_gather_kernel(const uint* __restrict__ msg, const int* __restrict__ gcur,
                          const uint* __restrict__ bedges, uint* __restrict__ agg16,
                          int n_nodes)
{
    __shared__ int  srcL[BCAP];      // 8 KB
    __shared__ int histL[BNODES];
    __shared__ int inclL[BNODES];
    __shared__ int cursL[BNODES];

    const int t = threadIdx.x;
    const int b = blockIdx.x;
    const int cnt = min(gcur[b], BCAP);
    const uint* be = bedges + (size_t)b * BCAP;

    if (t < BNODES) histL[t] = 0;
    __syncthreads();
    for (int i = t; i < cnt; i += 512)
        atomicAdd(&histL[be[i] & 63u], 1);
    __syncthreads();
    if (t < BNODES) inclL[t] = histL[t];
    for (int off = 1; off < BNODES; off <<= 1) {
        int add = 0;
        __syncthreads();
        if (t < BNODES && t >= off) add = inclL[t - off];
        __syncthreads();
        if (t < BNODES) inclL[t] += add;
    }
    __syncthreads();
    if (t < BNODES) cursL[t] = inclL[t] - histL[t];
    __syncthreads();
    for (int i = t; i < cnt; i += 512) {
        const uint p = be[i];
        const int pos = atomicAdd(&cursL[p & 63u], 1);
        srcL[pos] = (int)(p >> 6);
    }
    __syncthreads();

    const int lane = t & 63;
    const int w = t >> 6;            // 8 waves
    for (int dl = w; dl < BNODES; dl += 8) {
        const int node = b * BNODES + dl;
        if (node >= n_nodes) break;          // wave-uniform
        const int e1 = inclL[dl];
        const int e0 = e1 - histL[dl];
        float a0 = 0.f, a1 = 0.f;
        int i = e0;
        for (; i + 8 <= e1; i += 8) {
            uint m[8];
            #pragma unroll
            for (int k = 0; k < 8; ++k)
                m[k] = msg[(size_t)srcL[i + k] * 64 + lane];
            #pragma unroll
            for (int k = 0; k < 8; ++k) {
                a0 += __uint_as_float(m[k] << 16);
                a1 += __uint_as_float(m[k] & 0xffff0000u);
            }
        }
        for (; i + 4 <= e1; i += 4) {
            uint m[4];
            #pragma unroll
            for (int k = 0; k < 4; ++k)
                m[k] = msg[(size_t)srcL[i + k] * 64 + lane];
            #pragma unroll
            for (int k = 0; k < 4; ++k) {
                a0 += __uint_as_float(m[k] << 16);
                a1 += __uint_as_float(m[k] & 0xffff0000u);
            }
        }
        for (; i < e1; ++i) {
            const uint m = msg[(size_t)srcL[i] * 64 + lane];
            a0 += __uint_as_float(m << 16);
            a1 += __uint_as_float(m & 0xffff0000u);
        }
        agg16[(size_t)node * 64 + lane] = pack2(a0, a1);
    }
}

// lin2 A16 [round-13/14 proven]: A-fragments loaded directly as packed bf16
// uint4 (no pack VALU, half A traffic). Writes fp32 out + x residual.
__global__ __launch_bounds__(256, 2)
void lin2_a16_kernel(const uint4* __restrict__ agg16, const float* __restrict__ Wu,
                     const float* __restrict__ bu, const float* __restrict__ x,
                     float* __restrict__ out, int n_tiles)
{
    __shared__ uint4 Wl[128 * 16];
    const int t = threadIdx.x;
    for (int q = t; q < 2048; q += 256) {
        const int j = q >> 4, c = q & 15;
        const float4 lo = ((const float4*)(Wu + j * 128 + c * 8))[0];
        const float4 hi = ((const float4*)(Wu + j * 128 + c * 8))[1];
        uint4 pk;
        pk.x = pack2(lo.x, lo.y); pk.y = pack2(lo.z, lo.w);
        pk.z = pack2(hi.x, hi.y); pk.w = pack2(hi.z, hi.w);
        Wl[j * 16 + (c ^ (j & 15))] = pk;
    }
    __syncthreads();

    const int lane = t & 63;
    const int lo4 = lane & 15;
    const int g   = lane >> 4;

    float bias[8];
    #pragma unroll
    for (int ct = 0; ct < 8; ++ct) bias[ct] = bu[ct * 16 + lo4];

    const int wid = ((int)blockIdx.x * 256 + t) >> 6;
    const int nw  = ((int)gridDim.x * 256) >> 6;

    for (int tile = wid; tile < n_tiles; tile += nw) {
        const int arow = tile * 16 + lo4;
        bf16x8 afrag[4];
        #pragma unroll
        for (int ks = 0; ks < 4; ++ks) {
            const uint4 u = agg16[(size_t)arow * 16 + g * 4 + ks];
            afrag[ks] = *(const bf16x8*)&u;
        }

        f32x4 acc[8];
        #pragma unroll
        for (int ct = 0; ct < 8; ++ct)
            acc[ct] = (f32x4){bias[ct], bias[ct], bias[ct], bias[ct]};

        #pragma unroll
        for (int ks = 0; ks < 4; ++ks) {
            #pragma unroll
            for (int ct = 0; ct < 8; ++ct) {
                const int jrow = ct * 16 + lo4;
                const bf16x8 bfrag = *((const bf16x8*)&Wl[jrow * 16 + ((g * 4 + ks) ^ lo4)]);
                acc[ct] = __builtin_amdgcn_mfma_f32_16x16x32_bf16(afrag[ks], bfrag, acc[ct], 0, 0, 0);
            }
        }

        #pragma unroll
        for (int ct = 0; ct < 8; ++ct) {
            #pragma unroll
            for (int r = 0; r < 4; ++r) {
                const int orow = tile * 16 + g * 4 + r;
                const int ocol = ct * 16 + lo4;
                out[(size_t)orow * DIM + ocol] =
                    fmaxf(acc[ct][r], 0.f) + x[(size_t)orow * DIM + ocol];
            }
        }
    }
}

extern "C" void kernel_launch(void* const* d_in, const int* in_sizes, int n_in,
                              void* d_out, int out_size, void* d_ws, size_t ws_size,
                              hipStream_t stream)
{
    const float* x  = (const float*)d_in[0];
    const int*   ei = (const int*)d_in[1];
    const float* Wm = (const float*)d_in[2];
    const float* bm = (const float*)d_in[3];
    const float* Wu = (const float*)d_in[4];
    const float* bu = (const float*)d_in[5];

    const int N = in_sizes[0] / DIM;   // 100000
    const int E = in_sizes[1] / 2;     // 1600000
    const int nb  = (N + BNODES - 1) / BNODES;   // 1563
    const int ncb = (N + CNODES - 1) / CNODES;   // 98
    const int cb  = 782;               // coarse blocks (chunk 2047 <= CCHUNK)
    const int fb  = ncb * 8;           // 784 fine blocks
    const int lb  = 1024;              // lin1 blocks per fused kernel

    // ws: msg 25.6 | ccur+gcur 8.7KB | cedges 8.03 | bedges 12.85 | agg16 25.6
    // = 72.1MB; round 14 proved ws_size >= 72.1MB (a16 path was taken).
    char* ws = (char*)d_ws;
    ushort* msg = (ushort*)ws;
    size_t o = (size_t)N * DIM * sizeof(ushort);
    int* ccur = (int*)(ws + o); o += (size_t)NCMAX * 4;
    int* gcur = (int*)(ws + o); o += (size_t)NBMAX * 4;
    o = (o + 255) & ~(size_t)255;
    uint* cedges = (uint*)(ws + o); o += (size_t)ncb * CCAP * 4;
    o = (o + 255) & ~(size_t)255;
    uint* bedges = (uint*)(ws + o); o += (size_t)(nb + FB) * BCAP * 4;
    o = (o + 255) & ~(size_t)255;
    uint* agg16 = (uint*)(ws + o);

    float* out = (float*)d_out;
    const int n_tiles = N / 16;        // 6250
    const int half = n_tiles / 2;      // 3125

    // 0) zero cursors (ccur and gcur adjacent)
    hipMemsetAsync(ccur, 0, (size_t)(NCMAX + NBMAX) * 4, stream);

    // 1) fused A: coarse counting-sort (782) || lin1 tiles [0, half) (1024)
    fusedA_kernel<<<2 * cb + (lb - cb), 256, 0, stream>>>(
        x, Wm, bm, msg, 0, half, lb, ei, ccur, cedges, E, ncb, cb);

    // 2) fused B: fine scatter (784) || lin1 tiles [half, n_tiles) (1024)
    fusedB_kernel<<<2 * fb + (lb - fb), 256, 0, stream>>>(
        x, Wm, bm, msg, half, n_tiles - half, lb, ccur, cedges, gcur, bedges, ncb, fb);

    // 3) per-bucket LDS sort + pull gather (8-deep MLP) -> packed bf16 agg
    bucket_gather_kernel<<<nb, 512, 0, stream>>>((const uint*)msg, gcur, bedges, agg16, N);

    // 4) lin2: out = relu(agg @ Wu^T + bu) + x
    lin2_a16_kernel<<<1024, 256, 0, stream>>>((const uint4*)agg16, Wu, bu, x, out, n_tiles);
}

// Round 18
// 139.729 us; speedup vs baseline: 1.0910x; 1.0910x over previous
//
#include <hip/hip_runtime.h>
#include <hip/hip_bf16.h>

#define DIM 128
#define BNODES 64       // fine bucket = 64 dst nodes (dst>>6)
#define CNODES 1024     // coarse bucket = 1024 dst nodes (dst>>10)
#define NCMAX 128       // coarse cursor capacity (ncb = 98 for N=100000)
#define NBMAX 2048      // fine cursor capacity (nb = 1563)
#define CCAP 20480      // edges per coarse region (mean 16327, +32 sigma)
#define BCAP 2048       // edges per fine region (mean 1024, +32 sigma)
#define FB 16           // fine targets per coarse region (CNODES/BNODES)
#define CCHUNK 2048     // edges per coarse block (LDS staging capacity)

typedef __attribute__((ext_vector_type(8))) short bf16x8;
typedef __attribute__((ext_vector_type(4))) float f32x4;

__device__ inline ushort f2bf(float f) {
    uint u = __float_as_uint(f);
    u += 0x7fffu + ((u >> 16) & 1u);   // RNE
    return (ushort)(u >> 16);
}
__device__ inline uint pack2(float lo, float hi) {
    return (uint)f2bf(lo) | ((uint)f2bf(hi) << 16);
}

// ---- MFMA linear body (round-3-proven) --------------------------------------
// out[n][j] = relu(b[j] + sum_k in[n][k]*W[j][k]); one wave per 16-row tile.
// A/B share an assumed k-bijection (dot invariant); C layout m89-verified:
// col=lane&15, row=(lane>>4)*4+reg. Live set ~104 VGPR (round 6: 4/EU spills).
__device__ __forceinline__
void linear_body_bf16out(const float* in, const float* __restrict__ W,
                         const float* __restrict__ b, ushort* out,
                         int n_tiles, int bid, int nblocks, uint4* Wl)
{
    const int t = threadIdx.x;
    for (int q = t; q < 2048; q += 256) {
        const int j = q >> 4, c = q & 15;
        const float4 lo = ((const float4*)(W + j * 128 + c * 8))[0];
        const float4 hi = ((const float4*)(W + j * 128 + c * 8))[1];
        uint4 pk;
        pk.x = pack2(lo.x, lo.y); pk.y = pack2(lo.z, lo.w);
        pk.z = pack2(hi.x, hi.y); pk.w = pack2(hi.z, hi.w);
        Wl[j * 16 + (c ^ (j & 15))] = pk;
    }
    __syncthreads();

    const int lane = t & 63;
    const int lo4 = lane & 15;
    const int g   = lane >> 4;

    float bias[8];
    #pragma unroll
    for (int ct = 0; ct < 8; ++ct) bias[ct] = b[ct * 16 + lo4];

    const int wid = (bid * 256 + t) >> 6;
    const int nw  = (nblocks * 256) >> 6;

    for (int tile = wid; tile < n_tiles; tile += nw) {
        const int arow = tile * 16 + lo4;
        const float4* ap = (const float4*)(in + (size_t)arow * DIM + g * 32);
        float4 v[8];
        #pragma unroll
        for (int i = 0; i < 8; ++i) v[i] = ap[i];

        bf16x8 afrag[4];
        #pragma unroll
        for (int ks = 0; ks < 4; ++ks) {
            union { bf16x8 v8; uint u[4]; } a;
            a.u[0] = pack2(v[2*ks].x,   v[2*ks].y);
            a.u[1] = pack2(v[2*ks].z,   v[2*ks].w);
            a.u[2] = pack2(v[2*ks+1].x, v[2*ks+1].y);
            a.u[3] = pack2(v[2*ks+1].z, v[2*ks+1].w);
            afrag[ks] = a.v8;
        }

        f32x4 acc[8];
        #pragma unroll
        for (int ct = 0; ct < 8; ++ct)
            acc[ct] = (f32x4){bias[ct], bias[ct], bias[ct], bias[ct]};

        #pragma unroll
        for (int ks = 0; ks < 4; ++ks) {
            #pragma unroll
            for (int ct = 0; ct < 8; ++ct) {
                const int jrow = ct * 16 + lo4;
                const bf16x8 bfrag = *((const bf16x8*)&Wl[jrow * 16 + ((g * 4 + ks) ^ lo4)]);
                acc[ct] = __builtin_amdgcn_mfma_f32_16x16x32_bf16(afrag[ks], bfrag, acc[ct], 0, 0, 0);
            }
        }

        #pragma unroll
        for (int ct = 0; ct < 8; ++ct) {
            #pragma unroll
            for (int r = 0; r < 4; ++r) {
                const int orow = tile * 16 + g * 4 + r;
                const int ocol = ct * 16 + lo4;
                out[(size_t)orow * DIM + ocol] = f2bf(fmaxf(acc[ct][r], 0.f));
            }
        }
    }
}

// ---- fused: coarse partition (even bids) || lin1 (odd + tail bids) ----------
// Coarse blocks do a block-local counting sort (hist -> scan -> reorder into
// LDS staging, overlaid on the unused Wl) and then COALESCED per-region run
// copies. Parity interleave: every CU hosts both roles from t=0 -> real pipe
// overlap (round 15: fused beats serial by ~6.5us; round 16 confirmed).
__global__ __launch_bounds__(256, 2)
void lin1_coarse_kernel(const float* x, const float* __restrict__ Wm,
                        const float* __restrict__ bm, ushort* msg, int n_tiles,
                        const int* __restrict__ ei, int* __restrict__ ccur,
                        uint* __restrict__ cedges, int n_edges, int ncb, int cb)
{
    __shared__ uint4 Wl[128 * 16];   // 32 KB; coarse path overlays sort buffers

    const int bid = (int)blockIdx.x;
    bool coarse;
    int rid;   // role-local block id
    if (bid < 2 * cb) { coarse = !(bid & 1); rid = bid >> 1; }
    else              { coarse = false;      rid = cb + (bid - 2 * cb); }

    if (coarse) {
        uint*   packedL = (uint*)Wl;                    // 8 KB
        ushort* regionL = (ushort*)(packedL + CCHUNK);  // 4 KB
        int*    histC   = (int*)(regionL + CCHUNK);     // 512 B
        int*    startC  = histC + NCMAX;                // 512 B
        int*    gbaseC  = startC + NCMAX;               // 512 B
        int*    curC    = gbaseC + NCMAX;               // 512 B

        const int t = threadIdx.x;
        const int chunk = (n_edges + cb - 1) / cb;      // 2047 <= CCHUNK
        const int e0 = rid * chunk;
        const int e1 = min(e0 + chunk, n_edges);
        const int cnt = e1 - e0;

        if (t < NCMAX) histC[t] = 0;
        __syncthreads();
        for (int i = t; i < cnt; i += 256)
            atomicAdd(&histC[ei[n_edges + e0 + i] >> 10], 1);
        __syncthreads();
        if (t < NCMAX) startC[t] = histC[t];
        for (int off = 1; off < NCMAX; off <<= 1) {
            int add = 0;
            __syncthreads();
            if (t < NCMAX && t >= off) add = startC[t - off];
            __syncthreads();
            if (t < NCMAX) startC[t] += add;
        }
        __syncthreads();
        if (t < NCMAX) {
            const int excl = startC[t] - histC[t];
            startC[t] = excl;
            curC[t] = excl;
            gbaseC[t] = (t < ncb && histC[t]) ? atomicAdd(&ccur[t], histC[t]) : 0;
        }
        __syncthreads();
        for (int i = t; i < cnt; i += 256) {
            const int src = ei[e0 + i];
            const int dst = ei[n_edges + e0 + i];
            const int r = dst >> 10;
            const int pos = atomicAdd(&curC[r], 1);
            packedL[pos] = ((uint)src << 10) | (uint)(dst & 1023);
            regionL[pos] = (ushort)r;
        }
        __syncthreads();
        for (int i = t; i < cnt; i += 256) {
            const int r = regionL[i];
            const int off = gbaseC[r] + (i - startC[r]);
            if (off < CCAP)
                cedges[(size_t)r * CCAP + off] = packedL[i];   // coalesced runs
        }
    } else {
        linear_body_bf16out(x, Wm, bm, msg, n_tiles, rid,
                            (int)gridDim.x - cb, Wl);
    }
}

// Fine pass: refine each coarse region into its 16 fine buckets (dst>>6).
// Contiguous reads, ~1KB write runs. grid = ncb*8.  [round-12 proven]
__global__ __launch_bounds__(256)
void fine_scatter_kernel(const int* __restrict__ ccnt, const uint* __restrict__ cedges,
                         int* __restrict__ gcur, uint* __restrict__ bedges, int ncb)
{
    __shared__ int histL[FB];
    __shared__ int curL[FB];
    const int t = threadIdx.x;
    const int c = blockIdx.x >> 3;
    const int s = blockIdx.x & 7;
    const int cnt = min(ccnt[c], CCAP);
    const int chunk = (cnt + 7) / 8;
    const int e0 = s * chunk;
    const int e1 = min(e0 + chunk, cnt);
    if (t < FB) histL[t] = 0;
    __syncthreads();
    const uint* ce = cedges + (size_t)c * CCAP;
    for (int i = e0 + t; i < e1; i += 256)
        atomicAdd(&histL[(ce[i] & 1023u) >> 6], 1);
    __syncthreads();
    if (t < FB)
        curL[t] = histL[t] ? atomicAdd(&gcur[c * FB + t], histL[t]) : 0;
    __syncthreads();
    for (int i = e0 + t; i < e1; i += 256) {
        const uint p = ce[i];
        const uint dl = p & 1023u;
        const int f = (int)(dl >> 6);
        const int pos = atomicAdd(&curL[f], 1);
        if (pos < BCAP)
            bedges[(size_t)(c * FB + f) * BCAP + pos] = ((p >> 10) << 6) | (dl & 63u);
    }
}

// Per-bucket gather [round-12/14 proven]: hist + scan + sort (int LDS atomics),
// pull with 8-deep MLP, deposit packed-bf16 agg row (a16 handoff).
__global__ __launch_bounds__(512)
void bucket_gather_kernel(const uint* __restrict__ msg, const int* __restrict__ gcur,
                          const uint* __restrict__ bedges, uint* __restrict__ agg16,
                          int n_nodes)
{
    __shared__ int  srcL[BCAP];      // 8 KB
    __shared__ int histL[BNODES];
    __shared__ int inclL[BNODES];
    __shared__ int cursL[BNODES];

    const int t = threadIdx.x;
    const int b = blockIdx.x;
    const int cnt = min(gcur[b], BCAP);
    const uint* be = bedges + (size_t)b * BCAP;

    if (t < BNODES) histL[t] = 0;
    __syncthreads();
    for (int i = t; i < cnt; i += 512)
        atomicAdd(&histL[be[i] & 63u], 1);
    __syncthreads();
    if (t < BNODES) inclL[t] = histL[t];
    for (int off = 1; off < BNODES; off <<= 1) {
        int add = 0;
        __syncthreads();
        if (t < BNODES && t >= off) add = inclL[t - off];
        __syncthreads();
        if (t < BNODES) inclL[t] += add;
    }
    __syncthreads();
    if (t < BNODES) cursL[t] = inclL[t] - histL[t];
    __syncthreads();
    for (int i = t; i < cnt; i += 512) {
        const uint p = be[i];
        const int pos = atomicAdd(&cursL[p & 63u], 1);
        srcL[pos] = (int)(p >> 6);
    }
    __syncthreads();

    const int lane = t & 63;
    const int w = t >> 6;            // 8 waves
    for (int dl = w; dl < BNODES; dl += 8) {
        const int node = b * BNODES + dl;
        if (node >= n_nodes) break;          // wave-uniform
        const int e1 = inclL[dl];
        const int e0 = e1 - histL[dl];
        float a0 = 0.f, a1 = 0.f;
        int i = e0;
        for (; i + 8 <= e1; i += 8) {
            uint m[8];
            #pragma unroll
            for (int k = 0; k < 8; ++k)
                m[k] = msg[(size_t)srcL[i + k] * 64 + lane];
            #pragma unroll
            for (int k = 0; k < 8; ++k) {
                a0 += __uint_as_float(m[k] << 16);
                a1 += __uint_as_float(m[k] & 0xffff0000u);
            }
        }
        for (; i + 4 <= e1; i += 4) {
            uint m[4];
            #pragma unroll
            for (int k = 0; k < 4; ++k)
                m[k] = msg[(size_t)srcL[i + k] * 64 + lane];
            #pragma unroll
            for (int k = 0; k < 4; ++k) {
                a0 += __uint_as_float(m[k] << 16);
                a1 += __uint_as_float(m[k] & 0xffff0000u);
            }
        }
        for (; i < e1; ++i) {
            const uint m = msg[(size_t)srcL[i] * 64 + lane];
            a0 += __uint_as_float(m << 16);
            a1 += __uint_as_float(m & 0xffff0000u);
        }
        agg16[(size_t)node * 64 + lane] = pack2(a0, a1);
    }
}

// lin2 A16 [round-13/14 proven]: A-fragments loaded directly as packed bf16
// uint4 (no pack VALU, half A traffic). Writes fp32 out + x residual.
__global__ __launch_bounds__(256, 2)
void lin2_a16_kernel(const uint4* __restrict__ agg16, const float* __restrict__ Wu,
                     const float* __restrict__ bu, const float* __restrict__ x,
                     float* __restrict__ out, int n_tiles)
{
    __shared__ uint4 Wl[128 * 16];
    const int t = threadIdx.x;
    for (int q = t; q < 2048; q += 256) {
        const int j = q >> 4, c = q & 15;
        const float4 lo = ((const float4*)(Wu + j * 128 + c * 8))[0];
        const float4 hi = ((const float4*)(Wu + j * 128 + c * 8))[1];
        uint4 pk;
        pk.x = pack2(lo.x, lo.y); pk.y = pack2(lo.z, lo.w);
        pk.z = pack2(hi.x, hi.y); pk.w = pack2(hi.z, hi.w);
        Wl[j * 16 + (c ^ (j & 15))] = pk;
    }
    __syncthreads();

    const int lane = t & 63;
    const int lo4 = lane & 15;
    const int g   = lane >> 4;

    float bias[8];
    #pragma unroll
    for (int ct = 0; ct < 8; ++ct) bias[ct] = bu[ct * 16 + lo4];

    const int wid = ((int)blockIdx.x * 256 + t) >> 6;
    const int nw  = ((int)gridDim.x * 256) >> 6;

    for (int tile = wid; tile < n_tiles; tile += nw) {
        const int arow = tile * 16 + lo4;
        bf16x8 afrag[4];
        #pragma unroll
        for (int ks = 0; ks < 4; ++ks) {
            const uint4 u = agg16[(size_t)arow * 16 + g * 4 + ks];
            afrag[ks] = *(const bf16x8*)&u;
        }

        f32x4 acc[8];
        #pragma unroll
        for (int ct = 0; ct < 8; ++ct)
            acc[ct] = (f32x4){bias[ct], bias[ct], bias[ct], bias[ct]};

        #pragma unroll
        for (int ks = 0; ks < 4; ++ks) {
            #pragma unroll
            for (int ct = 0; ct < 8; ++ct) {
                const int jrow = ct * 16 + lo4;
                const bf16x8 bfrag = *((const bf16x8*)&Wl[jrow * 16 + ((g * 4 + ks) ^ lo4)]);
                acc[ct] = __builtin_amdgcn_mfma_f32_16x16x32_bf16(afrag[ks], bfrag, acc[ct], 0, 0, 0);
            }
        }

        #pragma unroll
        for (int ct = 0; ct < 8; ++ct) {
            #pragma unroll
            for (int r = 0; r < 4; ++r) {
                const int orow = tile * 16 + g * 4 + r;
                const int ocol = ct * 16 + lo4;
                out[(size_t)orow * DIM + ocol] =
                    fmaxf(acc[ct][r], 0.f) + x[(size_t)orow * DIM + ocol];
            }
        }
    }
}

extern "C" void kernel_launch(void* const* d_in, const int* in_sizes, int n_in,
                              void* d_out, int out_size, void* d_ws, size_t ws_size,
                              hipStream_t stream)
{
    const float* x  = (const float*)d_in[0];
    const int*   ei = (const int*)d_in[1];
    const float* Wm = (const float*)d_in[2];
    const float* bm = (const float*)d_in[3];
    const float* Wu = (const float*)d_in[4];
    const float* bu = (const float*)d_in[5];

    const int N = in_sizes[0] / DIM;   // 100000
    const int E = in_sizes[1] / 2;     // 1600000
    const int nb  = (N + BNODES - 1) / BNODES;   // 1563
    const int ncb = (N + CNODES - 1) / CNODES;   // 98
    const int cb  = 782;               // coarse blocks (chunk 2047 <= CCHUNK)

    // ws: msg 25.6 | ccur+gcur 8.7KB | cedges 8.03 | bedges 12.85 | agg16 25.6
    // = 72.1MB total; round 14 proved ws_size >= 72.1MB (a16 path was taken).
    char* ws = (char*)d_ws;
    ushort* msg = (ushort*)ws;
    size_t o = (size_t)N * DIM * sizeof(ushort);
    int* ccur = (int*)(ws + o); o += (size_t)NCMAX * 4;
    int* gcur = (int*)(ws + o); o += (size_t)NBMAX * 4;
    o = (o + 255) & ~(size_t)255;
    uint* cedges = (uint*)(ws + o); o += (size_t)ncb * CCAP * 4;
    o = (o + 255) & ~(size_t)255;
    uint* bedges = (uint*)(ws + o); o += (size_t)(nb + FB) * BCAP * 4;
    o = (o + 255) & ~(size_t)255;
    uint* agg16 = (uint*)(ws + o);

    float* out = (float*)d_out;
    const int n_tiles = N / 16;

    // 0) zero cursors (ccur and gcur adjacent)
    hipMemsetAsync(ccur, 0, (size_t)(NCMAX + NBMAX) * 4, stream);

    // 1) fused: coarse counting-sort partition (782 even bids) || lin1 (1266)
    lin1_coarse_kernel<<<2048, 256, 0, stream>>>(x, Wm, bm, msg, n_tiles,
                                                 ei, ccur, cedges, E, ncb, cb);

    // 2) fine partition: coarse regions -> 64-node buckets
    fine_scatter_kernel<<<ncb * 8, 256, 0, stream>>>(ccur, cedges, gcur, bedges, ncb);

    // 3) per-bucket LDS sort + pull gather (8-deep MLP) -> packed bf16 agg
    bucket_gather_kernel<<<nb, 512, 0, stream>>>((const uint*)msg, gcur, bedges, agg16, N);

    // 4) lin2: out = relu(agg @ Wu^T + bu) + x
    lin2_a16_kernel<<<1024, 256, 0, stream>>>((const uint4*)agg16, Wu, bu, x, out, n_tiles);
}